// Round 7
// baseline (536.719 us; speedup 1.0000x reference)
//
#include <hip/hip_runtime.h>
#include <hip/hip_bf16.h>

#define N_NODES 10000
#define D_FEAT 128
#define N_EDGES 640000
#define CAP 128        // bucket capacity; P(Poisson(64) >= 128) ~ 7e-13/node
#define CNT_STRIDE 32  // one counter per 128B line (full TCC line, no false sharing)
#define ROWS 32        // feat rows per GEMM block
#define PROBE_ITERS 12

// MEASUREMENT ROUND: pipeline byte-identical to round 5 (131.7 us ref).
// Added AFTER the real pipeline:
//   - 4x empty-kernel dispatches        -> measures per-dispatch overhead g
//   - 1x scatter-core probe (12x body)  -> lands top-1 in rocprof with PMC;
//     its dur_us = 12*T_core (kernel-only scatter cost, no gap)
// Solves {g, T_scatter} from round-6's T_scatter + g = 29.3.

// ---------------- K1: h = relu(feat @ W + b) -> bf16 ----------------
__device__ __forceinline__ void fma4(float4& a, float s, const float4& w) {
  a.x += s * w.x; a.y += s * w.y; a.z += s * w.z; a.w += s * w.w;
}

__global__ __launch_bounds__(256) void gemm_relu_kernel(
    const float* __restrict__ feat, const float* __restrict__ W,
    const float* __restrict__ b, unsigned* __restrict__ h_u,
    uint4* __restrict__ cnt4) {
  __shared__ float fs[ROWS][D_FEAT];  // 16 KB
  const int t = threadIdx.x;
  {
    const int g = blockIdx.x * 256 + t;
    if (g < N_NODES * CNT_STRIDE / 4) cnt4[g] = make_uint4(0u, 0u, 0u, 0u);
  }
  const int row0 = blockIdx.x * ROWS;
  const float4* __restrict__ feat4 = (const float4*)feat;
#pragma unroll
  for (int i = 0; i < 4; ++i) {
    const int g = row0 * 32 + i * 256 + t;  // float4 index into feat
    if (g < N_NODES * 32) ((float4*)&fs[0][0])[i * 256 + t] = feat4[g];
  }
  __syncthreads();

  const int c4 = t & 31;   // col-group (4 cols)
  const int r8 = t >> 5;   // row-slot: rows r8, r8+8, r8+16, r8+24
  const float4* __restrict__ W4 = (const float4*)W;
  float4 a0 = {0,0,0,0}, a1 = {0,0,0,0}, a2 = {0,0,0,0}, a3 = {0,0,0,0};
#pragma unroll 4
  for (int k0 = 0; k0 < D_FEAT; k0 += 4) {
    const float4 f0 = *(const float4*)&fs[r8][k0];
    const float4 f1 = *(const float4*)&fs[r8 + 8][k0];
    const float4 f2 = *(const float4*)&fs[r8 + 16][k0];
    const float4 f3 = *(const float4*)&fs[r8 + 24][k0];
    const float4 w0 = W4[(k0 + 0) * 32 + c4];
    const float4 w1 = W4[(k0 + 1) * 32 + c4];
    const float4 w2 = W4[(k0 + 2) * 32 + c4];
    const float4 w3 = W4[(k0 + 3) * 32 + c4];
    fma4(a0, f0.x, w0); fma4(a0, f0.y, w1); fma4(a0, f0.z, w2); fma4(a0, f0.w, w3);
    fma4(a1, f1.x, w0); fma4(a1, f1.y, w1); fma4(a1, f1.z, w2); fma4(a1, f1.w, w3);
    fma4(a2, f2.x, w0); fma4(a2, f2.y, w1); fma4(a2, f2.z, w2); fma4(a2, f2.w, w3);
    fma4(a3, f3.x, w0); fma4(a3, f3.y, w1); fma4(a3, f3.z, w2); fma4(a3, f3.w, w3);
  }

  const float4 bb = ((const float4*)b)[c4];
  float4 accs[4] = {a0, a1, a2, a3};
#pragma unroll
  for (int i = 0; i < 4; ++i) {
    const int row = row0 + r8 + 8 * i;
    if (row < N_NODES) {
      const float v0 = fmaxf(accs[i].x + bb.x, 0.f);
      const float v1 = fmaxf(accs[i].y + bb.y, 0.f);
      const float v2 = fmaxf(accs[i].z + bb.z, 0.f);
      const float v3 = fmaxf(accs[i].w + bb.w, 0.f);
      __hip_bfloat162 p0 = __float22bfloat162_rn(make_float2(v0, v1));
      __hip_bfloat162 p1 = __float22bfloat162_rn(make_float2(v2, v3));
      uint2 u;
      u.x = *reinterpret_cast<unsigned*>(&p0);
      u.y = *reinterpret_cast<unsigned*>(&p1);
      ((uint2*)h_u)[row * 32 + c4] = u;
    }
  }
}

// ---------------- K2: direct atomic scatter into per-dst buckets -------
__global__ __launch_bounds__(256) void scatter_kernel(
    const int4* __restrict__ src4, const int4* __restrict__ dst4,
    unsigned* __restrict__ cnt, unsigned* __restrict__ elist) {
  const int i = blockIdx.x * 256 + threadIdx.x;   // 625*256 == N_EDGES/4
  const int4 s = src4[i];
  const int4 d = dst4[i];
  unsigned p;
  p = atomicAdd(&cnt[(unsigned)d.x * CNT_STRIDE], 1u); if (p < CAP) elist[((unsigned)d.x << 7) + p] = (unsigned)s.x;
  p = atomicAdd(&cnt[(unsigned)d.y * CNT_STRIDE], 1u); if (p < CAP) elist[((unsigned)d.y << 7) + p] = (unsigned)s.y;
  p = atomicAdd(&cnt[(unsigned)d.z * CNT_STRIDE], 1u); if (p < CAP) elist[((unsigned)d.z << 7) + p] = (unsigned)s.z;
  p = atomicAdd(&cnt[(unsigned)d.w * CNT_STRIDE], 1u); if (p < CAP) elist[((unsigned)d.w << 7) + p] = (unsigned)s.w;
}

// ---------------- K3: per-dst max aggregation + residual ----------------
__device__ __forceinline__ void accum_bf16(unsigned u, float& lo, float& hi) {
  lo = fmaxf(lo, __uint_as_float(u << 16));
  hi = fmaxf(hi, __uint_as_float(u & 0xffff0000u));
}

__global__ __launch_bounds__(128) void aggregate_kernel(
    const uint4* __restrict__ h16, const float4* __restrict__ feat4,
    const unsigned* __restrict__ cnt, const unsigned* __restrict__ elist,
    float4* __restrict__ out4) {
  const int d = blockIdx.x;
  const int t = threadIdx.x;
  const int slot8 = t >> 4;   // 0..7
  const int j = t & 15;       // 16-lane group within the row

  __shared__ unsigned sl[CAP];
  __shared__ float red[16][8];

  const unsigned n = min(cnt[(unsigned)d * CNT_STRIDE], (unsigned)CAP);
  if ((unsigned)t < n) sl[t] = elist[((unsigned)d << 7) + (unsigned)t];
  __syncthreads();

  float m0 = 0.f, m1 = 0.f, m2 = 0.f, m3 = 0.f,
        m4 = 0.f, m5 = 0.f, m6 = 0.f, m7 = 0.f;  // relu >= 0
  unsigned bpos = 0;
  for (; bpos + 16 <= n; bpos += 16) {
    const unsigned sA = sl[bpos + slot8];
    const unsigned sB = sl[bpos + 8 + slot8];
    const uint4 qA = h16[sA * 16 + j];
    const uint4 qB = h16[sB * 16 + j];
    accum_bf16(qA.x, m0, m1); accum_bf16(qA.y, m2, m3);
    accum_bf16(qA.z, m4, m5); accum_bf16(qA.w, m6, m7);
    accum_bf16(qB.x, m0, m1); accum_bf16(qB.y, m2, m3);
    accum_bf16(qB.z, m4, m5); accum_bf16(qB.w, m6, m7);
  }
  for (; bpos < n; bpos += 8) {
    if (bpos + slot8 < n) {
      const uint4 q = h16[sl[bpos + slot8] * 16 + j];
      accum_bf16(q.x, m0, m1); accum_bf16(q.y, m2, m3);
      accum_bf16(q.z, m4, m5); accum_bf16(q.w, m6, m7);
    }
  }

  m0 = fmaxf(m0, __shfl_xor(m0, 16)); m1 = fmaxf(m1, __shfl_xor(m1, 16));
  m2 = fmaxf(m2, __shfl_xor(m2, 16)); m3 = fmaxf(m3, __shfl_xor(m3, 16));
  m4 = fmaxf(m4, __shfl_xor(m4, 16)); m5 = fmaxf(m5, __shfl_xor(m5, 16));
  m6 = fmaxf(m6, __shfl_xor(m6, 16)); m7 = fmaxf(m7, __shfl_xor(m7, 16));
  m0 = fmaxf(m0, __shfl_xor(m0, 32)); m1 = fmaxf(m1, __shfl_xor(m1, 32));
  m2 = fmaxf(m2, __shfl_xor(m2, 32)); m3 = fmaxf(m3, __shfl_xor(m3, 32));
  m4 = fmaxf(m4, __shfl_xor(m4, 32)); m5 = fmaxf(m5, __shfl_xor(m5, 32));
  m6 = fmaxf(m6, __shfl_xor(m6, 32)); m7 = fmaxf(m7, __shfl_xor(m7, 32));

  if (t >= 64 && t < 80) {
    red[t - 64][0] = m0; red[t - 64][1] = m1; red[t - 64][2] = m2; red[t - 64][3] = m3;
    red[t - 64][4] = m4; red[t - 64][5] = m5; red[t - 64][6] = m6; red[t - 64][7] = m7;
  }
  __syncthreads();
  if (t < 16) {
    m0 = fmaxf(m0, red[t][0]); m1 = fmaxf(m1, red[t][1]);
    m2 = fmaxf(m2, red[t][2]); m3 = fmaxf(m3, red[t][3]);
    m4 = fmaxf(m4, red[t][4]); m5 = fmaxf(m5, red[t][5]);
    m6 = fmaxf(m6, red[t][6]); m7 = fmaxf(m7, red[t][7]);
    const float4 fA = feat4[d * 32 + t * 2];
    const float4 fB = feat4[d * 32 + t * 2 + 1];
    out4[d * 32 + t * 2]     = make_float4(m0 + fA.x, m1 + fA.y, m2 + fA.z, m3 + fA.w);
    out4[d * 32 + t * 2 + 1] = make_float4(m4 + fB.x, m5 + fB.y, m6 + fB.z, m7 + fB.w);
  }
}

// ---------------- probes (scratch-only, run AFTER out is written) -------
__global__ void nop_kernel() {}

// scatter core body x PROBE_ITERS into scratch. No init needed: atomicAdd
// on poison still exercises the atomic path; stores are wrapped (p & 127)
// so addresses stay in-bounds and store traffic is identical every iter.
__global__ __launch_bounds__(256) void scatter_probe_kernel(
    const int4* __restrict__ src4, const int4* __restrict__ dst4,
    unsigned* __restrict__ cnt2, unsigned* __restrict__ elist2) {
  const int i = blockIdx.x * 256 + threadIdx.x;
  const int4 s = src4[i];
  const int4 d = dst4[i];
  for (int it = 0; it < PROBE_ITERS; ++it) {
    unsigned p;
    p = atomicAdd(&cnt2[(unsigned)d.x * CNT_STRIDE], 1u); elist2[((unsigned)d.x << 7) + (p & (CAP - 1))] = (unsigned)s.x;
    p = atomicAdd(&cnt2[(unsigned)d.y * CNT_STRIDE], 1u); elist2[((unsigned)d.y << 7) + (p & (CAP - 1))] = (unsigned)s.y;
    p = atomicAdd(&cnt2[(unsigned)d.z * CNT_STRIDE], 1u); elist2[((unsigned)d.z << 7) + (p & (CAP - 1))] = (unsigned)s.z;
    p = atomicAdd(&cnt2[(unsigned)d.w * CNT_STRIDE], 1u); elist2[((unsigned)d.w << 7) + (p & (CAP - 1))] = (unsigned)s.w;
  }
}

extern "C" void kernel_launch(void* const* d_in, const int* in_sizes, int n_in,
                              void* d_out, int out_size, void* d_ws, size_t ws_size,
                              hipStream_t stream) {
  const float* feat   = (const float*)d_in[0];
  const float* W_pool = (const float*)d_in[1];
  const float* b_pool = (const float*)d_in[2];
  const int* edge_src = (const int*)d_in[3];
  const int* edge_dst = (const int*)d_in[4];
  float* out = (float*)d_out;

  // workspace layout
  char* ws = (char*)d_ws;
  unsigned* h_u    = (unsigned*)(ws);                 // 2,560,000 B (bf16 h)
  unsigned* cnt    = (unsigned*)(ws + 2560000);       // 1,280,000 B (padded)
  unsigned* elist  = (unsigned*)(ws + 3840000);       // 5,120,000 B
  unsigned* cnt2   = (unsigned*)(ws + 8960000);       // 1,280,000 B (probe scratch)
  unsigned* elist2 = (unsigned*)(ws + 10240000);      // 5,120,000 B (probe scratch)

  // real pipeline (byte-identical to round 5)
  gemm_relu_kernel<<<(N_NODES + ROWS - 1) / ROWS, 256, 0, stream>>>(
      feat, W_pool, b_pool, h_u, (uint4*)cnt);
  scatter_kernel<<<N_EDGES / 4 / 256, 256, 0, stream>>>(
      (const int4*)edge_src, (const int4*)edge_dst, cnt, elist);
  aggregate_kernel<<<N_NODES, 128, 0, stream>>>(
      (const uint4*)h_u, (const float4*)feat, cnt, elist, (float4*)out);

  // probes: 4x empty dispatches (gap measurement) + 12x scatter core (PMC)
  nop_kernel<<<1, 64, 0, stream>>>();
  nop_kernel<<<1, 64, 0, stream>>>();
  nop_kernel<<<1, 64, 0, stream>>>();
  nop_kernel<<<1, 64, 0, stream>>>();
  scatter_probe_kernel<<<N_EDGES / 4 / 256, 256, 0, stream>>>(
      (const int4*)edge_src, (const int4*)edge_dst, cnt2, elist2);
}

// Round 8
// 132.063 us; speedup vs baseline: 4.0641x; 4.0641x over previous
//
#include <hip/hip_runtime.h>
#include <hip/hip_bf16.h>

#define N_NODES 10000
#define D_FEAT 128
#define N_EDGES 640000
#define NX 8           // pseudo-XCD sub-buckets per dst (blockIdx & 7)
#define CELL_CAP 32    // slots per (dst, pseudo-XCD) cell; P(Poisson(8)>=32)~1e-10
#define CNT_PER_D 16   // counter stride per dst: 16 uints = 64B line (8 used)
#define ROWS 32        // feat rows per GEMM block

// Round-7 probe finding: scatter is bound by partial-line multi-XCD
// write-allocate churn (56B of HBM writeback per 4B store; 36 MB/pass at
// ~1 TB/s). Fix: per-dst buckets split into 8 pseudo-XCD-private cells
// (x = blockIdx&7) so each 128B cell is dirtied by ONE XCD's L2 and
// written back once. Counters: cnt[d*16+x] (one 64B line per dst, same
// line-lock rate as the round-2 padded layout that measured best).

// ---------------- K1: h = relu(feat @ W + b) -> bf16 ----------------
__device__ __forceinline__ void fma4(float4& a, float s, const float4& w) {
  a.x += s * w.x; a.y += s * w.y; a.z += s * w.z; a.w += s * w.w;
}

__global__ __launch_bounds__(256) void gemm_relu_kernel(
    const float* __restrict__ feat, const float* __restrict__ W,
    const float* __restrict__ b, unsigned* __restrict__ h_u,
    uint4* __restrict__ cnt4) {
  __shared__ float fs[ROWS][D_FEAT];  // 16 KB
  const int t = threadIdx.x;
  {
    // zero counters: 10000*16 uints = 40000 uint4; 313*256=80128 threads
    const int g = blockIdx.x * 256 + t;
    if (g < N_NODES * CNT_PER_D / 4) cnt4[g] = make_uint4(0u, 0u, 0u, 0u);
  }
  const int row0 = blockIdx.x * ROWS;
  const float4* __restrict__ feat4 = (const float4*)feat;
#pragma unroll
  for (int i = 0; i < 4; ++i) {
    const int g = row0 * 32 + i * 256 + t;  // float4 index into feat
    if (g < N_NODES * 32) ((float4*)&fs[0][0])[i * 256 + t] = feat4[g];
  }
  __syncthreads();

  const int c4 = t & 31;   // col-group (4 cols)
  const int r8 = t >> 5;   // row-slot: rows r8, r8+8, r8+16, r8+24
  const float4* __restrict__ W4 = (const float4*)W;
  float4 a0 = {0,0,0,0}, a1 = {0,0,0,0}, a2 = {0,0,0,0}, a3 = {0,0,0,0};
#pragma unroll 4
  for (int k0 = 0; k0 < D_FEAT; k0 += 4) {
    const float4 f0 = *(const float4*)&fs[r8][k0];
    const float4 f1 = *(const float4*)&fs[r8 + 8][k0];
    const float4 f2 = *(const float4*)&fs[r8 + 16][k0];
    const float4 f3 = *(const float4*)&fs[r8 + 24][k0];
    const float4 w0 = W4[(k0 + 0) * 32 + c4];
    const float4 w1 = W4[(k0 + 1) * 32 + c4];
    const float4 w2 = W4[(k0 + 2) * 32 + c4];
    const float4 w3 = W4[(k0 + 3) * 32 + c4];
    fma4(a0, f0.x, w0); fma4(a0, f0.y, w1); fma4(a0, f0.z, w2); fma4(a0, f0.w, w3);
    fma4(a1, f1.x, w0); fma4(a1, f1.y, w1); fma4(a1, f1.z, w2); fma4(a1, f1.w, w3);
    fma4(a2, f2.x, w0); fma4(a2, f2.y, w1); fma4(a2, f2.z, w2); fma4(a2, f2.w, w3);
    fma4(a3, f3.x, w0); fma4(a3, f3.y, w1); fma4(a3, f3.z, w2); fma4(a3, f3.w, w3);
  }

  const float4 bb = ((const float4*)b)[c4];
  float4 accs[4] = {a0, a1, a2, a3};
#pragma unroll
  for (int i = 0; i < 4; ++i) {
    const int row = row0 + r8 + 8 * i;
    if (row < N_NODES) {
      const float v0 = fmaxf(accs[i].x + bb.x, 0.f);
      const float v1 = fmaxf(accs[i].y + bb.y, 0.f);
      const float v2 = fmaxf(accs[i].z + bb.z, 0.f);
      const float v3 = fmaxf(accs[i].w + bb.w, 0.f);
      __hip_bfloat162 p0 = __float22bfloat162_rn(make_float2(v0, v1));
      __hip_bfloat162 p1 = __float22bfloat162_rn(make_float2(v2, v3));
      uint2 u;
      u.x = *reinterpret_cast<unsigned*>(&p0);
      u.y = *reinterpret_cast<unsigned*>(&p1);
      ((uint2*)h_u)[row * 32 + c4] = u;
    }
  }
}

// ---------------- K2: XCD-private atomic scatter -----------------------
// elist cell for (d, x): 32 slots at elist[(d<<8) + (x<<5)]. All stores
// to a cell come from blocks with the same blockIdx&7 -> one XCD's L2
// owns its lines -> single writeback instead of ~5 partial ones.
__global__ __launch_bounds__(256) void scatter_kernel(
    const int4* __restrict__ src4, const int4* __restrict__ dst4,
    unsigned* __restrict__ cnt, unsigned* __restrict__ elist) {
  const int i = blockIdx.x * 256 + threadIdx.x;   // 625*256 == N_EDGES/4
  const unsigned x = (unsigned)blockIdx.x & 7u;
  const int4 s = src4[i];
  const int4 d = dst4[i];
  unsigned p;
  p = atomicAdd(&cnt[((unsigned)d.x << 4) + x], 1u);
  if (p < CELL_CAP) elist[((unsigned)d.x << 8) + (x << 5) + p] = (unsigned)s.x;
  p = atomicAdd(&cnt[((unsigned)d.y << 4) + x], 1u);
  if (p < CELL_CAP) elist[((unsigned)d.y << 8) + (x << 5) + p] = (unsigned)s.y;
  p = atomicAdd(&cnt[((unsigned)d.z << 4) + x], 1u);
  if (p < CELL_CAP) elist[((unsigned)d.z << 8) + (x << 5) + p] = (unsigned)s.z;
  p = atomicAdd(&cnt[((unsigned)d.w << 4) + x], 1u);
  if (p < CELL_CAP) elist[((unsigned)d.w << 8) + (x << 5) + p] = (unsigned)s.w;
}

// ---------------- K3: per-dst max aggregation + residual ----------------
__device__ __forceinline__ void accum_bf16(unsigned u, float& lo, float& hi) {
  lo = fmaxf(lo, __uint_as_float(u << 16));
  hi = fmaxf(hi, __uint_as_float(u & 0xffff0000u));
}

__global__ __launch_bounds__(128) void aggregate_kernel(
    const uint4* __restrict__ h16, const float4* __restrict__ feat4,
    const unsigned* __restrict__ cnt, const unsigned* __restrict__ elist,
    float4* __restrict__ out4) {
  const int d = blockIdx.x;
  const int t = threadIdx.x;
  const int slot8 = t >> 4;   // 0..7
  const int j = t & 15;       // 16-lane group within the row

  __shared__ unsigned sl[NX * CELL_CAP];  // up to 256 staged edge ids
  __shared__ unsigned scnt[NX];
  __shared__ unsigned offs[NX + 1];
  __shared__ float red[16][8];

  if (t < NX) scnt[t] = min(cnt[((unsigned)d << 4) + (unsigned)t], (unsigned)CELL_CAP);
  __syncthreads();
  if (t == 0) {
    unsigned r = 0;
#pragma unroll
    for (int x = 0; x < NX; ++x) { offs[x] = r; r += scnt[x]; }
    offs[NX] = r;
  }
  __syncthreads();
  const unsigned n = offs[NX];
  {
    // stage 8 cells compactly: 8 cells x 16 threads, two rounds
    const int x = t >> 4;
    const unsigned k = (unsigned)(t & 15);
    const unsigned cx = scnt[x];
    const unsigned base = ((unsigned)d << 8) + ((unsigned)x << 5);
    const unsigned o = offs[x];
    if (k < cx) sl[o + k] = elist[base + k];
    if (k + 16 < cx) sl[o + k + 16] = elist[base + k + 16];
  }
  __syncthreads();

  float m0 = 0.f, m1 = 0.f, m2 = 0.f, m3 = 0.f,
        m4 = 0.f, m5 = 0.f, m6 = 0.f, m7 = 0.f;  // relu >= 0
  unsigned bpos = 0;
  for (; bpos + 16 <= n; bpos += 16) {
    const unsigned sA = sl[bpos + slot8];
    const unsigned sB = sl[bpos + 8 + slot8];
    const uint4 qA = h16[sA * 16 + j];
    const uint4 qB = h16[sB * 16 + j];
    accum_bf16(qA.x, m0, m1); accum_bf16(qA.y, m2, m3);
    accum_bf16(qA.z, m4, m5); accum_bf16(qA.w, m6, m7);
    accum_bf16(qB.x, m0, m1); accum_bf16(qB.y, m2, m3);
    accum_bf16(qB.z, m4, m5); accum_bf16(qB.w, m6, m7);
  }
  for (; bpos < n; bpos += 8) {
    if (bpos + slot8 < n) {
      const uint4 q = h16[sl[bpos + slot8] * 16 + j];
      accum_bf16(q.x, m0, m1); accum_bf16(q.y, m2, m3);
      accum_bf16(q.z, m4, m5); accum_bf16(q.w, m6, m7);
    }
  }

  // reduce 8 slots: xor-16 and xor-32 within wave, then cross-wave via LDS
  m0 = fmaxf(m0, __shfl_xor(m0, 16)); m1 = fmaxf(m1, __shfl_xor(m1, 16));
  m2 = fmaxf(m2, __shfl_xor(m2, 16)); m3 = fmaxf(m3, __shfl_xor(m3, 16));
  m4 = fmaxf(m4, __shfl_xor(m4, 16)); m5 = fmaxf(m5, __shfl_xor(m5, 16));
  m6 = fmaxf(m6, __shfl_xor(m6, 16)); m7 = fmaxf(m7, __shfl_xor(m7, 16));
  m0 = fmaxf(m0, __shfl_xor(m0, 32)); m1 = fmaxf(m1, __shfl_xor(m1, 32));
  m2 = fmaxf(m2, __shfl_xor(m2, 32)); m3 = fmaxf(m3, __shfl_xor(m3, 32));
  m4 = fmaxf(m4, __shfl_xor(m4, 32)); m5 = fmaxf(m5, __shfl_xor(m5, 32));
  m6 = fmaxf(m6, __shfl_xor(m6, 32)); m7 = fmaxf(m7, __shfl_xor(m7, 32));

  if (t >= 64 && t < 80) {
    red[t - 64][0] = m0; red[t - 64][1] = m1; red[t - 64][2] = m2; red[t - 64][3] = m3;
    red[t - 64][4] = m4; red[t - 64][5] = m5; red[t - 64][6] = m6; red[t - 64][7] = m7;
  }
  __syncthreads();
  if (t < 16) {
    m0 = fmaxf(m0, red[t][0]); m1 = fmaxf(m1, red[t][1]);
    m2 = fmaxf(m2, red[t][2]); m3 = fmaxf(m3, red[t][3]);
    m4 = fmaxf(m4, red[t][4]); m5 = fmaxf(m5, red[t][5]);
    m6 = fmaxf(m6, red[t][6]); m7 = fmaxf(m7, red[t][7]);
    const float4 fA = feat4[d * 32 + t * 2];
    const float4 fB = feat4[d * 32 + t * 2 + 1];
    out4[d * 32 + t * 2]     = make_float4(m0 + fA.x, m1 + fA.y, m2 + fA.z, m3 + fA.w);
    out4[d * 32 + t * 2 + 1] = make_float4(m4 + fB.x, m5 + fB.y, m6 + fB.z, m7 + fB.w);
  }
}

extern "C" void kernel_launch(void* const* d_in, const int* in_sizes, int n_in,
                              void* d_out, int out_size, void* d_ws, size_t ws_size,
                              hipStream_t stream) {
  const float* feat   = (const float*)d_in[0];
  const float* W_pool = (const float*)d_in[1];
  const float* b_pool = (const float*)d_in[2];
  const int* edge_src = (const int*)d_in[3];
  const int* edge_dst = (const int*)d_in[4];
  float* out = (float*)d_out;

  // workspace layout
  char* ws = (char*)d_ws;
  unsigned* h_u   = (unsigned*)(ws);                 //  2,560,000 B (bf16 h)
  unsigned* cnt   = (unsigned*)(ws + 2560000);       //    640,000 B (16 uints/dst, 64B line)
  unsigned* elist = (unsigned*)(ws + 3200000);       // 10,240,000 B (10000*8*32*4)

  gemm_relu_kernel<<<(N_NODES + ROWS - 1) / ROWS, 256, 0, stream>>>(
      feat, W_pool, b_pool, h_u, (uint4*)cnt);
  scatter_kernel<<<N_EDGES / 4 / 256, 256, 0, stream>>>(
      (const int4*)edge_src, (const int4*)edge_dst, cnt, elist);
  aggregate_kernel<<<N_NODES, 128, 0, stream>>>(
      (const uint4*)h_u, (const float4*)feat, cnt, elist, (float4*)out);
}

// Round 9
// 126.798 us; speedup vs baseline: 4.2329x; 1.0415x over previous
//
#include <hip/hip_runtime.h>
#include <hip/hip_bf16.h>

#define N_NODES 10000
#define D_FEAT 128
#define N_EDGES 640000
#define CAP 128        // bucket capacity; P(Poisson(64) >= 128) ~ 7e-13/node
#define CNT_STRIDE 32  // one counter per 128B line (round-2/5 best layout)
#define ROWS 32        // feat rows per GEMM block
#define NBLK_SCAT 625  // 625*256*4 == N_EDGES
#define NBLK_GEMM 313  // 313*32 >= N_NODES

// Round-8 lesson: T_scatter ~27-29 us is invariant across THREE scatter
// layouts -> it's the per-store sub-line churn (~56B writeback per 4B
// store, round-7 probe), not line ownership. Scatter is latency-bound
// (0.1% VALU, 12% BW) -> HIDE it instead: one heterogeneous dispatch
// where blocks 0..624 scatter and blocks 625..937 do the GEMM (fully
// independent inputs). cnt zeroing moves to a stream-ordered memset.

// ---------------- K1: fused scatter (blocks 0..624) + gemm (625..937) ---
__device__ __forceinline__ void fma4(float4& a, float s, const float4& w) {
  a.x += s * w.x; a.y += s * w.y; a.z += s * w.z; a.w += s * w.w;
}

__global__ __launch_bounds__(256) void gemm_scatter_kernel(
    const float* __restrict__ feat, const float* __restrict__ W,
    const float* __restrict__ b, const int4* __restrict__ src4,
    const int4* __restrict__ dst4, unsigned* __restrict__ h_u,
    unsigned* __restrict__ cnt, unsigned* __restrict__ elist) {
  __shared__ float fs[ROWS][D_FEAT];  // used by gemm blocks only (16 KB)
  const int t = threadIdx.x;

  if (blockIdx.x < NBLK_SCAT) {
    // ---- scatter: 4 INDEPENDENT atomic reservations, then 4 stores ----
    // (single latency round-trip per thread instead of 4 serial ones)
    const int i = blockIdx.x * 256 + t;
    const int4 s = src4[i];
    const int4 d = dst4[i];
    const unsigned p0 = atomicAdd(&cnt[(unsigned)d.x * CNT_STRIDE], 1u);
    const unsigned p1 = atomicAdd(&cnt[(unsigned)d.y * CNT_STRIDE], 1u);
    const unsigned p2 = atomicAdd(&cnt[(unsigned)d.z * CNT_STRIDE], 1u);
    const unsigned p3 = atomicAdd(&cnt[(unsigned)d.w * CNT_STRIDE], 1u);
    if (p0 < CAP) elist[((unsigned)d.x << 7) + p0] = (unsigned)s.x;
    if (p1 < CAP) elist[((unsigned)d.y << 7) + p1] = (unsigned)s.y;
    if (p2 < CAP) elist[((unsigned)d.z << 7) + p2] = (unsigned)s.z;
    if (p3 < CAP) elist[((unsigned)d.w << 7) + p3] = (unsigned)s.w;
    return;
  }

  // ---- gemm: h = relu(feat @ W + b) -> bf16 ----
  const int row0 = (blockIdx.x - NBLK_SCAT) * ROWS;
  const float4* __restrict__ feat4 = (const float4*)feat;
#pragma unroll
  for (int i = 0; i < 4; ++i) {
    const int g = row0 * 32 + i * 256 + t;  // float4 index into feat
    if (g < N_NODES * 32) ((float4*)&fs[0][0])[i * 256 + t] = feat4[g];
  }
  __syncthreads();

  const int c4 = t & 31;   // col-group (4 cols)
  const int r8 = t >> 5;   // row-slot: rows r8, r8+8, r8+16, r8+24
  const float4* __restrict__ W4 = (const float4*)W;
  float4 a0 = {0,0,0,0}, a1 = {0,0,0,0}, a2 = {0,0,0,0}, a3 = {0,0,0,0};
#pragma unroll 4
  for (int k0 = 0; k0 < D_FEAT; k0 += 4) {
    const float4 f0 = *(const float4*)&fs[r8][k0];
    const float4 f1 = *(const float4*)&fs[r8 + 8][k0];
    const float4 f2 = *(const float4*)&fs[r8 + 16][k0];
    const float4 f3 = *(const float4*)&fs[r8 + 24][k0];
    const float4 w0 = W4[(k0 + 0) * 32 + c4];
    const float4 w1 = W4[(k0 + 1) * 32 + c4];
    const float4 w2 = W4[(k0 + 2) * 32 + c4];
    const float4 w3 = W4[(k0 + 3) * 32 + c4];
    fma4(a0, f0.x, w0); fma4(a0, f0.y, w1); fma4(a0, f0.z, w2); fma4(a0, f0.w, w3);
    fma4(a1, f1.x, w0); fma4(a1, f1.y, w1); fma4(a1, f1.z, w2); fma4(a1, f1.w, w3);
    fma4(a2, f2.x, w0); fma4(a2, f2.y, w1); fma4(a2, f2.z, w2); fma4(a2, f2.w, w3);
    fma4(a3, f3.x, w0); fma4(a3, f3.y, w1); fma4(a3, f3.z, w2); fma4(a3, f3.w, w3);
  }

  const float4 bb = ((const float4*)b)[c4];
  float4 accs[4] = {a0, a1, a2, a3};
#pragma unroll
  for (int i = 0; i < 4; ++i) {
    const int row = row0 + r8 + 8 * i;
    if (row < N_NODES) {
      const float v0 = fmaxf(accs[i].x + bb.x, 0.f);
      const float v1 = fmaxf(accs[i].y + bb.y, 0.f);
      const float v2 = fmaxf(accs[i].z + bb.z, 0.f);
      const float v3 = fmaxf(accs[i].w + bb.w, 0.f);
      __hip_bfloat162 p0 = __float22bfloat162_rn(make_float2(v0, v1));
      __hip_bfloat162 p1 = __float22bfloat162_rn(make_float2(v2, v3));
      uint2 u;
      u.x = *reinterpret_cast<unsigned*>(&p0);
      u.y = *reinterpret_cast<unsigned*>(&p1);
      ((uint2*)h_u)[row * 32 + c4] = u;
    }
  }
}

// ---------------- K2: per-dst max aggregation + residual ----------------
__device__ __forceinline__ void accum_bf16(unsigned u, float& lo, float& hi) {
  lo = fmaxf(lo, __uint_as_float(u << 16));
  hi = fmaxf(hi, __uint_as_float(u & 0xffff0000u));
}

__global__ __launch_bounds__(128) void aggregate_kernel(
    const uint4* __restrict__ h16, const float4* __restrict__ feat4,
    const unsigned* __restrict__ cnt, const unsigned* __restrict__ elist,
    float4* __restrict__ out4) {
  const int d = blockIdx.x;
  const int t = threadIdx.x;
  const int slot8 = t >> 4;   // 0..7
  const int j = t & 15;       // 16-lane group within the row

  __shared__ unsigned sl[CAP];
  __shared__ float red[16][8];

  const unsigned n = min(cnt[(unsigned)d * CNT_STRIDE], (unsigned)CAP);
  if ((unsigned)t < n) sl[t] = elist[((unsigned)d << 7) + (unsigned)t];
  __syncthreads();

  float m0 = 0.f, m1 = 0.f, m2 = 0.f, m3 = 0.f,
        m4 = 0.f, m5 = 0.f, m6 = 0.f, m7 = 0.f;  // relu >= 0
  unsigned bpos = 0;
  for (; bpos + 16 <= n; bpos += 16) {
    const unsigned sA = sl[bpos + slot8];
    const unsigned sB = sl[bpos + 8 + slot8];
    const uint4 qA = h16[sA * 16 + j];
    const uint4 qB = h16[sB * 16 + j];
    accum_bf16(qA.x, m0, m1); accum_bf16(qA.y, m2, m3);
    accum_bf16(qA.z, m4, m5); accum_bf16(qA.w, m6, m7);
    accum_bf16(qB.x, m0, m1); accum_bf16(qB.y, m2, m3);
    accum_bf16(qB.z, m4, m5); accum_bf16(qB.w, m6, m7);
  }
  for (; bpos < n; bpos += 8) {
    if (bpos + slot8 < n) {
      const uint4 q = h16[sl[bpos + slot8] * 16 + j];
      accum_bf16(q.x, m0, m1); accum_bf16(q.y, m2, m3);
      accum_bf16(q.z, m4, m5); accum_bf16(q.w, m6, m7);
    }
  }

  // reduce 8 slots: xor-16 and xor-32 within wave, then cross-wave via LDS
  m0 = fmaxf(m0, __shfl_xor(m0, 16)); m1 = fmaxf(m1, __shfl_xor(m1, 16));
  m2 = fmaxf(m2, __shfl_xor(m2, 16)); m3 = fmaxf(m3, __shfl_xor(m3, 16));
  m4 = fmaxf(m4, __shfl_xor(m4, 16)); m5 = fmaxf(m5, __shfl_xor(m5, 16));
  m6 = fmaxf(m6, __shfl_xor(m6, 16)); m7 = fmaxf(m7, __shfl_xor(m7, 16));
  m0 = fmaxf(m0, __shfl_xor(m0, 32)); m1 = fmaxf(m1, __shfl_xor(m1, 32));
  m2 = fmaxf(m2, __shfl_xor(m2, 32)); m3 = fmaxf(m3, __shfl_xor(m3, 32));
  m4 = fmaxf(m4, __shfl_xor(m4, 32)); m5 = fmaxf(m5, __shfl_xor(m5, 32));
  m6 = fmaxf(m6, __shfl_xor(m6, 32)); m7 = fmaxf(m7, __shfl_xor(m7, 32));

  if (t >= 64 && t < 80) {
    red[t - 64][0] = m0; red[t - 64][1] = m1; red[t - 64][2] = m2; red[t - 64][3] = m3;
    red[t - 64][4] = m4; red[t - 64][5] = m5; red[t - 64][6] = m6; red[t - 64][7] = m7;
  }
  __syncthreads();
  if (t < 16) {
    m0 = fmaxf(m0, red[t][0]); m1 = fmaxf(m1, red[t][1]);
    m2 = fmaxf(m2, red[t][2]); m3 = fmaxf(m3, red[t][3]);
    m4 = fmaxf(m4, red[t][4]); m5 = fmaxf(m5, red[t][5]);
    m6 = fmaxf(m6, red[t][6]); m7 = fmaxf(m7, red[t][7]);
    const float4 fA = feat4[d * 32 + t * 2];
    const float4 fB = feat4[d * 32 + t * 2 + 1];
    out4[d * 32 + t * 2]     = make_float4(m0 + fA.x, m1 + fA.y, m2 + fA.z, m3 + fA.w);
    out4[d * 32 + t * 2 + 1] = make_float4(m4 + fB.x, m5 + fB.y, m6 + fB.z, m7 + fB.w);
  }
}

extern "C" void kernel_launch(void* const* d_in, const int* in_sizes, int n_in,
                              void* d_out, int out_size, void* d_ws, size_t ws_size,
                              hipStream_t stream) {
  const float* feat   = (const float*)d_in[0];
  const float* W_pool = (const float*)d_in[1];
  const float* b_pool = (const float*)d_in[2];
  const int* edge_src = (const int*)d_in[3];
  const int* edge_dst = (const int*)d_in[4];
  float* out = (float*)d_out;

  // workspace layout
  char* ws = (char*)d_ws;
  unsigned* h_u   = (unsigned*)(ws);                 // 2,560,000 B (bf16 h)
  unsigned* cnt   = (unsigned*)(ws + 2560000);       // 1,280,000 B (padded 128B/counter)
  unsigned* elist = (unsigned*)(ws + 3840000);       // 5,120,000 B (10000*128*4)

  // zero counters (stream-ordered, before any scatter atomic)
  hipMemsetAsync(cnt, 0, (size_t)N_NODES * CNT_STRIDE * 4, stream);

  gemm_scatter_kernel<<<NBLK_SCAT + NBLK_GEMM, 256, 0, stream>>>(
      feat, W_pool, b_pool, (const int4*)edge_src, (const int4*)edge_dst,
      h_u, cnt, elist);
  aggregate_kernel<<<N_NODES, 128, 0, stream>>>(
      (const uint4*)h_u, (const float4*)feat, cnt, elist, (float4*)out);
}

// Round 10
// 119.040 us; speedup vs baseline: 4.5087x; 1.0652x over previous
//
#include <hip/hip_runtime.h>
#include <hip/hip_bf16.h>

#define N_NODES 10000
#define D_FEAT 128
#define N_EDGES 640000
#define CAP 128        // bucket capacity; P(Poisson(64) >= 128) ~ 7e-13/node
#define CNT_STRIDE 32  // one counter per 128B line (round-2/5 best layout)
#define ROWS 32        // feat rows per GEMM block
#define NBLK_SCAT 625  // 625*256*4 == N_EDGES
#define NBLK_GEMM 313  // 313*32 >= N_NODES
#define NPASS 10       // dst-range passes: dst>>10 in [0,9]; 512KB window/pass

// Round-9 profile: fused kernel 52us, WRITE_SIZE 37.5MB (payload ~9MB) ->
// partial-line writeback churn confirmed. Round-8 null => churn is
// TEMPORAL (lines evicted part-filled under 5.1MB random store pressure),
// not XCD ownership. Fix: phase the scatter by dst range. Edges are read
// ONCE into registers; 10 passes issue only edges with dst>>10 == g, so
// each pass's stores land in a 512KB elist window that fits L2 -> every
// line fills completely before one writeback.

// ---------------- K1: fused scatter (blocks 0..624) + gemm (625..937) ---
__device__ __forceinline__ void fma4(float4& a, float s, const float4& w) {
  a.x += s * w.x; a.y += s * w.y; a.z += s * w.z; a.w += s * w.w;
}

__global__ __launch_bounds__(256) void gemm_scatter_kernel(
    const float* __restrict__ feat, const float* __restrict__ W,
    const float* __restrict__ b, const int4* __restrict__ src4,
    const int4* __restrict__ dst4, unsigned* __restrict__ h_u,
    unsigned* __restrict__ cnt, unsigned* __restrict__ elist) {
  __shared__ float fs[ROWS][D_FEAT];  // used by gemm blocks only (16 KB)
  const int t = threadIdx.x;

  if (blockIdx.x < NBLK_SCAT) {
    // ---- dst-range phased scatter ----
    const int i = blockIdx.x * 256 + t;
    const int4 s = src4[i];
    const int4 d = dst4[i];
    const int gx = d.x >> 10, gy = d.y >> 10, gz = d.z >> 10, gw = d.w >> 10;
    for (int g = 0; g < NPASS; ++g) {
      unsigned p;
      if (gx == g) {
        p = atomicAdd(&cnt[(unsigned)d.x * CNT_STRIDE], 1u);
        if (p < CAP) elist[((unsigned)d.x << 7) + p] = (unsigned)s.x;
      }
      if (gy == g) {
        p = atomicAdd(&cnt[(unsigned)d.y * CNT_STRIDE], 1u);
        if (p < CAP) elist[((unsigned)d.y << 7) + p] = (unsigned)s.y;
      }
      if (gz == g) {
        p = atomicAdd(&cnt[(unsigned)d.z * CNT_STRIDE], 1u);
        if (p < CAP) elist[((unsigned)d.z << 7) + p] = (unsigned)s.z;
      }
      if (gw == g) {
        p = atomicAdd(&cnt[(unsigned)d.w * CNT_STRIDE], 1u);
        if (p < CAP) elist[((unsigned)d.w << 7) + p] = (unsigned)s.w;
      }
    }
    return;
  }

  // ---- gemm: h = relu(feat @ W + b) -> bf16 ----
  const int row0 = (blockIdx.x - NBLK_SCAT) * ROWS;
  const float4* __restrict__ feat4 = (const float4*)feat;
#pragma unroll
  for (int i = 0; i < 4; ++i) {
    const int g = row0 * 32 + i * 256 + t;  // float4 index into feat
    if (g < N_NODES * 32) ((float4*)&fs[0][0])[i * 256 + t] = feat4[g];
  }
  __syncthreads();

  const int c4 = t & 31;   // col-group (4 cols)
  const int r8 = t >> 5;   // row-slot: rows r8, r8+8, r8+16, r8+24
  const float4* __restrict__ W4 = (const float4*)W;
  float4 a0 = {0,0,0,0}, a1 = {0,0,0,0}, a2 = {0,0,0,0}, a3 = {0,0,0,0};
#pragma unroll 4
  for (int k0 = 0; k0 < D_FEAT; k0 += 4) {
    const float4 f0 = *(const float4*)&fs[r8][k0];
    const float4 f1 = *(const float4*)&fs[r8 + 8][k0];
    const float4 f2 = *(const float4*)&fs[r8 + 16][k0];
    const float4 f3 = *(const float4*)&fs[r8 + 24][k0];
    const float4 w0 = W4[(k0 + 0) * 32 + c4];
    const float4 w1 = W4[(k0 + 1) * 32 + c4];
    const float4 w2 = W4[(k0 + 2) * 32 + c4];
    const float4 w3 = W4[(k0 + 3) * 32 + c4];
    fma4(a0, f0.x, w0); fma4(a0, f0.y, w1); fma4(a0, f0.z, w2); fma4(a0, f0.w, w3);
    fma4(a1, f1.x, w0); fma4(a1, f1.y, w1); fma4(a1, f1.z, w2); fma4(a1, f1.w, w3);
    fma4(a2, f2.x, w0); fma4(a2, f2.y, w1); fma4(a2, f2.z, w2); fma4(a2, f2.w, w3);
    fma4(a3, f3.x, w0); fma4(a3, f3.y, w1); fma4(a3, f3.z, w2); fma4(a3, f3.w, w3);
  }

  const float4 bb = ((const float4*)b)[c4];
  float4 accs[4] = {a0, a1, a2, a3};
#pragma unroll
  for (int i = 0; i < 4; ++i) {
    const int row = row0 + r8 + 8 * i;
    if (row < N_NODES) {
      const float v0 = fmaxf(accs[i].x + bb.x, 0.f);
      const float v1 = fmaxf(accs[i].y + bb.y, 0.f);
      const float v2 = fmaxf(accs[i].z + bb.z, 0.f);
      const float v3 = fmaxf(accs[i].w + bb.w, 0.f);
      __hip_bfloat162 p0 = __float22bfloat162_rn(make_float2(v0, v1));
      __hip_bfloat162 p1 = __float22bfloat162_rn(make_float2(v2, v3));
      uint2 u;
      u.x = *reinterpret_cast<unsigned*>(&p0);
      u.y = *reinterpret_cast<unsigned*>(&p1);
      ((uint2*)h_u)[row * 32 + c4] = u;
    }
  }
}

// ---------------- K2: per-dst max aggregation + residual ----------------
__device__ __forceinline__ void accum_bf16(unsigned u, float& lo, float& hi) {
  lo = fmaxf(lo, __uint_as_float(u << 16));
  hi = fmaxf(hi, __uint_as_float(u & 0xffff0000u));
}

__global__ __launch_bounds__(128) void aggregate_kernel(
    const uint4* __restrict__ h16, const float4* __restrict__ feat4,
    const unsigned* __restrict__ cnt, const unsigned* __restrict__ elist,
    float4* __restrict__ out4) {
  const int d = blockIdx.x;
  const int t = threadIdx.x;
  const int slot8 = t >> 4;   // 0..7
  const int j = t & 15;       // 16-lane group within the row

  __shared__ unsigned sl[CAP];
  __shared__ float red[16][8];

  const unsigned n = min(cnt[(unsigned)d * CNT_STRIDE], (unsigned)CAP);
  if ((unsigned)t < n) sl[t] = elist[((unsigned)d << 7) + (unsigned)t];
  __syncthreads();

  float m0 = 0.f, m1 = 0.f, m2 = 0.f, m3 = 0.f,
        m4 = 0.f, m5 = 0.f, m6 = 0.f, m7 = 0.f;  // relu >= 0
  unsigned bpos = 0;
  for (; bpos + 16 <= n; bpos += 16) {
    const unsigned sA = sl[bpos + slot8];
    const unsigned sB = sl[bpos + 8 + slot8];
    const uint4 qA = h16[sA * 16 + j];
    const uint4 qB = h16[sB * 16 + j];
    accum_bf16(qA.x, m0, m1); accum_bf16(qA.y, m2, m3);
    accum_bf16(qA.z, m4, m5); accum_bf16(qA.w, m6, m7);
    accum_bf16(qB.x, m0, m1); accum_bf16(qB.y, m2, m3);
    accum_bf16(qB.z, m4, m5); accum_bf16(qB.w, m6, m7);
  }
  for (; bpos < n; bpos += 8) {
    if (bpos + slot8 < n) {
      const uint4 q = h16[sl[bpos + slot8] * 16 + j];
      accum_bf16(q.x, m0, m1); accum_bf16(q.y, m2, m3);
      accum_bf16(q.z, m4, m5); accum_bf16(q.w, m6, m7);
    }
  }

  // reduce 8 slots: xor-16 and xor-32 within wave, then cross-wave via LDS
  m0 = fmaxf(m0, __shfl_xor(m0, 16)); m1 = fmaxf(m1, __shfl_xor(m1, 16));
  m2 = fmaxf(m2, __shfl_xor(m2, 16)); m3 = fmaxf(m3, __shfl_xor(m3, 16));
  m4 = fmaxf(m4, __shfl_xor(m4, 16)); m5 = fmaxf(m5, __shfl_xor(m5, 16));
  m6 = fmaxf(m6, __shfl_xor(m6, 16)); m7 = fmaxf(m7, __shfl_xor(m7, 16));
  m0 = fmaxf(m0, __shfl_xor(m0, 32)); m1 = fmaxf(m1, __shfl_xor(m1, 32));
  m2 = fmaxf(m2, __shfl_xor(m2, 32)); m3 = fmaxf(m3, __shfl_xor(m3, 32));
  m4 = fmaxf(m4, __shfl_xor(m4, 32)); m5 = fmaxf(m5, __shfl_xor(m5, 32));
  m6 = fmaxf(m6, __shfl_xor(m6, 32)); m7 = fmaxf(m7, __shfl_xor(m7, 32));

  if (t >= 64 && t < 80) {
    red[t - 64][0] = m0; red[t - 64][1] = m1; red[t - 64][2] = m2; red[t - 64][3] = m3;
    red[t - 64][4] = m4; red[t - 64][5] = m5; red[t - 64][6] = m6; red[t - 64][7] = m7;
  }
  __syncthreads();
  if (t < 16) {
    m0 = fmaxf(m0, red[t][0]); m1 = fmaxf(m1, red[t][1]);
    m2 = fmaxf(m2, red[t][2]); m3 = fmaxf(m3, red[t][3]);
    m4 = fmaxf(m4, red[t][4]); m5 = fmaxf(m5, red[t][5]);
    m6 = fmaxf(m6, red[t][6]); m7 = fmaxf(m7, red[t][7]);
    const float4 fA = feat4[d * 32 + t * 2];
    const float4 fB = feat4[d * 32 + t * 2 + 1];
    out4[d * 32 + t * 2]     = make_float4(m0 + fA.x, m1 + fA.y, m2 + fA.z, m3 + fA.w);
    out4[d * 32 + t * 2 + 1] = make_float4(m4 + fB.x, m5 + fB.y, m6 + fB.z, m7 + fB.w);
  }
}

extern "C" void kernel_launch(void* const* d_in, const int* in_sizes, int n_in,
                              void* d_out, int out_size, void* d_ws, size_t ws_size,
                              hipStream_t stream) {
  const float* feat   = (const float*)d_in[0];
  const float* W_pool = (const float*)d_in[1];
  const float* b_pool = (const float*)d_in[2];
  const int* edge_src = (const int*)d_in[3];
  const int* edge_dst = (const int*)d_in[4];
  float* out = (float*)d_out;

  // workspace layout
  char* ws = (char*)d_ws;
  unsigned* h_u   = (unsigned*)(ws);                 // 2,560,000 B (bf16 h)
  unsigned* cnt   = (unsigned*)(ws + 2560000);       // 1,280,000 B (padded 128B/counter)
  unsigned* elist = (unsigned*)(ws + 3840000);       // 5,120,000 B (10000*128*4)

  // zero counters (stream-ordered, before any scatter atomic)
  hipMemsetAsync(cnt, 0, (size_t)N_NODES * CNT_STRIDE * 4, stream);

  gemm_scatter_kernel<<<NBLK_SCAT + NBLK_GEMM, 256, 0, stream>>>(
      feat, W_pool, b_pool, (const int4*)edge_src, (const int4*)edge_dst,
      h_u, cnt, elist);
  aggregate_kernel<<<N_NODES, 128, 0, stream>>>(
      (const uint4*)h_u, (const float4*)feat, cnt, elist, (float4*)out);
}